// Round 13
// baseline (586.790 us; speedup 1.0000x reference)
//
#include <hip/hip_runtime.h>
#include <hip/hip_bf16.h>
#include <math.h>

#define HID 128
constexpr int cN  = 50000;   // nodes
constexpr int cE  = 600000;  // edges
constexpr int cG  = 512;     // graphs
constexpr int cZV = 1800;    // z vocab
constexpr int cP  = 600000;  // positions
constexpr int NB  = (cN + 511) / 512;   // scan blocks = 98
constexpr int GATHER_BLOCKS = 2048;     // 8 blocks/CU x 256 CU

typedef unsigned int uint32;
typedef unsigned short ushort16;
typedef __attribute__((ext_vector_type(8))) short bf16x8s;
typedef __attribute__((ext_vector_type(4))) float f32x4;

__device__ __forceinline__ float eluf(float v) {
    return v > 0.f ? v : (__expf(v) - 1.f);
}

__device__ __forceinline__ float2 bf2f2(uint32 u) {
    float2 r;
    r.x = __uint_as_float(u << 16);
    r.y = __uint_as_float(u & 0xffff0000u);
    return r;
}

__device__ __forceinline__ ushort16 f2bf(float f) {
    uint32 u = __float_as_uint(f);
    u += 0x7fffu + ((u >> 16) & 1u);
    return (ushort16)(u >> 16);
}

__device__ __forceinline__ uint32 f2bf2pack(float a, float b) {
    return (uint32)f2bf(a) | ((uint32)f2bf(b) << 16);
}

// ---- fused prep: eps, deg histogram, graph starts, z->bf16, zWe1 dot ----
__global__ void prep_kernel(const int* __restrict__ pos_batch, const int* __restrict__ batch,
                            const int* __restrict__ dst, const float* __restrict__ z,
                            const float* __restrict__ We1,
                            int* __restrict__ eps, int* __restrict__ gs,
                            int* __restrict__ deg, ushort16* __restrict__ zb,
                            float* __restrict__ zWe1) {
    int i = blockIdx.x * blockDim.x + threadIdx.x;
    if (i < cP) {
        int cur = pos_batch[i];
        int prev = (i == 0) ? -1 : pos_batch[i - 1];
        for (int e = prev + 1; e <= cur; ++e) eps[e] = i;
        if (i == cP - 1)
            for (int e = cur + 1; e <= cE; ++e) eps[e] = cP;
    }
    if (i < cE) atomicAdd(&deg[dst[i]], 1);
    if (i < cZV * HID) zb[i] = f2bf(z[i]);
    if (i < cZV) {
        float acc = 0.f;
        #pragma unroll 8
        for (int k = 0; k < HID; ++k) acc += z[i * HID + k] * We1[k];
        zWe1[i] = acc;
    }
    if (i <= cG) {
        int lo = 0, hi = cN;
        while (lo < hi) {
            int mid = (lo + hi) >> 1;
            if (batch[mid] < i) lo = mid + 1; else hi = mid;
        }
        gs[i] = lo;
    }
}

// ---- transpose+cast weights for MFMA: Wt[m][c][k] = bf16(W[m][k][c]) ----
// m=0: c1W1 ; m=1..3: cW0[l] ; m=4..6: cW1[l] ; m=7..9: cWe[l]
__global__ void wt_kernel(const float* __restrict__ c1W1, const float* __restrict__ cW0,
                          const float* __restrict__ cW1, const float* __restrict__ cWe,
                          ushort16* __restrict__ Wt) {
    int m = blockIdx.x;
    const float* src = (m == 0) ? c1W1
                     : (m <= 3) ? (cW0 + (size_t)(m - 1) * HID * HID)
                     : (m <= 6) ? (cW1 + (size_t)(m - 4) * HID * HID)
                                : (cWe + (size_t)(m - 7) * HID * HID);
    ushort16* dstp = Wt + (size_t)m * HID * HID;
    for (int idx = threadIdx.x; idx < HID * HID; idx += 256) {
        int c = idx >> 7, k = idx & 127;
        dstp[idx] = f2bf(src[(size_t)k * HID + c]);
    }
}

// ---- MFMA zWe tables: zWe[l][v][:] = bf16( zb[v][:] @ We[l] ) ----
__global__ __launch_bounds__(256) void zwe_mfma(
    const ushort16* __restrict__ zb,    // [cZV][128] bf16
    const ushort16* __restrict__ WtE,   // [3][128][128] bf16 transposed
    ushort16* __restrict__ zWeb)        // [3][cZV][128] bf16
{
    int l = blockIdx.y;
    const ushort16* Wt = WtE + (size_t)l * HID * HID;
    ushort16* outp = zWeb + (size_t)l * cZV * HID;
    int wv = threadIdx.x >> 6;
    int lane = threadIdx.x & 63;
    int row0 = blockIdx.x * 64 + wv * 16;
    int r = lane & 15;
    int g = lane >> 4;
    int grow = row0 + r;
    bf16x8s zero8 = {0, 0, 0, 0, 0, 0, 0, 0};
    bf16x8s xf[4];
    #pragma unroll
    for (int kk = 0; kk < 4; ++kk)
        xf[kk] = (grow < cZV) ? *(const bf16x8s*)(zb + (size_t)grow * HID + kk * 32 + g * 8)
                              : zero8;
    f32x4 acc[8];
    #pragma unroll
    for (int ct = 0; ct < 8; ++ct) acc[ct] = (f32x4){0.f, 0.f, 0.f, 0.f};
    #pragma unroll
    for (int kk = 0; kk < 4; ++kk) {
        #pragma unroll
        for (int ct = 0; ct < 8; ++ct) {
            bf16x8s wf = *(const bf16x8s*)(Wt + (size_t)(ct * 16 + r) * HID + kk * 32 + g * 8);
            acc[ct] = __builtin_amdgcn_mfma_f32_16x16x32_bf16(wf, xf[kk], acc[ct], 0, 0, 0);
        }
    }
    if (grow < cZV) {
        #pragma unroll
        for (int ct = 0; ct < 8; ++ct) {
            int c0 = ct * 16 + g * 4;
            uint2 pk;
            pk.x = f2bf2pack(acc[ct][0], acc[ct][1]);
            pk.y = f2bf2pack(acc[ct][2], acc[ct][3]);
            *(uint2*)(outp + (size_t)grow * HID + c0) = pk;
        }
    }
}

// ======================= CSR scan chain =======================
__global__ void scan1(const int* __restrict__ deg, int* __restrict__ rowptr,
                      int* __restrict__ bsum) {
    __shared__ int t[512];
    int i = blockIdx.x * 512 + threadIdx.x;
    int v = (i < cN) ? deg[i] : 0;
    t[threadIdx.x] = v;
    __syncthreads();
    for (int off = 1; off < 512; off <<= 1) {
        int add = (threadIdx.x >= off) ? t[threadIdx.x - off] : 0;
        __syncthreads();
        t[threadIdx.x] += add;
        __syncthreads();
    }
    if (i < cN) rowptr[i + 1] = t[threadIdx.x];
    if (threadIdx.x == 511) bsum[blockIdx.x] = t[511];
}

__global__ void scan2(const int* __restrict__ bsum, int* __restrict__ boffs) {
    __shared__ int t[128];
    int i = threadIdx.x;
    int v = (i < NB) ? bsum[i] : 0;
    t[i] = v;
    __syncthreads();
    for (int off = 1; off < 128; off <<= 1) {
        int add = (i >= off) ? t[i - off] : 0;
        __syncthreads();
        t[i] += add;
        __syncthreads();
    }
    if (i < NB) boffs[i] = t[i] - v;   // exclusive prefix
}

__global__ void scan3(int* __restrict__ rowptr, int* __restrict__ cursor,
                      const int* __restrict__ boffs) {
    int i = blockIdx.x * blockDim.x + threadIdx.x;
    if (i == 0) { rowptr[0] = 0; cursor[0] = 0; }
    if (i < cN) {
        int val = rowptr[i + 1] + boffs[i >> 9];
        rowptr[i + 1] = val;
        cursor[i + 1] = val;
    }
}

__global__ void csr_scatter(const int* __restrict__ dst, int* __restrict__ cursor,
                            int* __restrict__ csr_eid) {
    int e = blockIdx.x * blockDim.x + threadIdx.x;
    if (e >= cE) return;
    int p = atomicAdd(&cursor[dst[e]], 1);
    csr_eid[p] = e;
}

// ---- wave-parallel deterministic sort (bitonic over 64 lanes) + erec build ----
// erec[i] = (src, cnt | (pstart<<8), pidx0, bits(penc0))
__device__ __forceinline__ int4 make_erec(int e, const int* __restrict__ src,
                                          const int* __restrict__ eps,
                                          const int* __restrict__ pos_index,
                                          const float* __restrict__ pos_enc) {
    int s = eps[e], t = eps[e + 1];
    int cnt = t - s;
    int4 r;
    r.x = src[e];
    r.y = cnt | (s << 8);
    if (cnt >= 1) { r.z = pos_index[s]; r.w = __float_as_int(pos_enc[s]); }
    else          { r.z = 0;            r.w = 0; }
    return r;
}

__global__ __launch_bounds__(256) void csr_sort_erec_wave(
    const int* __restrict__ rowptr, int* __restrict__ eid,
    const int* __restrict__ src, const int* __restrict__ eps,
    const int* __restrict__ pos_index, const float* __restrict__ pos_enc,
    int4* __restrict__ erec)
{
    int wid = threadIdx.x >> 6;
    int lane = threadIdx.x & 63;
    int n = blockIdx.x * 4 + wid;
    if (n >= cN) return;
    int a = rowptr[n], b = rowptr[n + 1];
    int d = b - a;
    if (d > 64) {
        if (lane == 0) {
            for (int i = a + 1; i < b; ++i) {
                int v = eid[i];
                int j = i - 1;
                while (j >= a && eid[j] > v) { eid[j + 1] = eid[j]; --j; }
                eid[j + 1] = v;
            }
            for (int i = a; i < b; ++i)
                erec[i] = make_erec(eid[i], src, eps, pos_index, pos_enc);
        }
        return;
    }
    int v = (lane < d) ? eid[a + lane] : 0x7fffffff;
    #pragma unroll
    for (int k = 2; k <= 64; k <<= 1) {
        for (int j = k >> 1; j > 0; j >>= 1) {
            int w = __shfl_xor(v, j);
            bool up    = ((lane & k) == 0);
            bool lower = ((lane & j) == 0);
            v = (up == lower) ? min(v, w) : max(v, w);
        }
    }
    if (lane < d)
        erec[a + lane] = make_erec(v, src, eps, pos_index, pos_enc);
}

// ---- per-edge z contribution, 4 channels/lane (half-wave layout) ----
__device__ __forceinline__ float4 zcalc4(int4 r, int l5,
                                         const ushort16* __restrict__ zWe,
                                         const int* __restrict__ pos_index,
                                         const float* __restrict__ pos_enc) {
    float w = __int_as_float(r.w);
    uint2 zu = ((const uint2*)(zWe + (size_t)r.z * HID))[l5];
    float2 za = bf2f2(zu.x), zc = bf2f2(zu.y);
    float4 z;
    z.x = w * za.x; z.y = w * za.y; z.z = w * zc.x; z.w = w * zc.y;
    int cnt = r.y & 255;
    if (cnt >= 2) {
        int s = ((uint32)r.y) >> 8;
        for (int p = s + 1; p < s + cnt; ++p) {
            float wp = pos_enc[p];
            uint2 zp = ((const uint2*)(zWe + (size_t)pos_index[p] * HID))[l5];
            float2 pa = bf2f2(zp.x), pb = bf2f2(zp.y);
            z.x += wp * pa.x; z.y += wp * pa.y; z.z += wp * pb.x; z.w += wp * pb.y;
        }
    }
    return z;
}

__device__ __forceinline__ float zcalc1(int4 r,
                                        const float* __restrict__ zWe1,
                                        const int* __restrict__ pos_index,
                                        const float* __restrict__ pos_enc) {
    float a = __int_as_float(r.w) * zWe1[r.z];
    int cnt = r.y & 255;
    if (cnt >= 2) {
        int s = ((uint32)r.y) >> 8;
        for (int p = s + 1; p < s + cnt; ++p)
            a += pos_enc[p] * zWe1[pos_index[p]];
    }
    return a;
}

// fold one edge (4 channels/lane) into acc
__device__ __forceinline__ void edge_acc(int4 r, uint2 xu, int l5,
                                         const ushort16* __restrict__ zWe,
                                         const int* __restrict__ pos_index,
                                         const float* __restrict__ pos_enc,
                                         float4 b4, float4& acc) {
    float4 z = zcalc4(r, l5, zWe, pos_index, pos_enc);
    float2 xa = bf2f2(xu.x), xc = bf2f2(xu.y);
    acc.x += fmaxf(xa.x + z.x + b4.x, 0.f);
    acc.y += fmaxf(xa.y + z.y + b4.y, 0.f);
    acc.z += fmaxf(xc.x + z.z + b4.z, 0.f);
    acc.w += fmaxf(xc.y + z.w + b4.w, 0.f);
}

// ======================= conv1 (gather, grid-stride, fused node stage A) ============
__global__ __launch_bounds__(256) void conv1_gather(
    const int* __restrict__ rowptr, const int4* __restrict__ erec,
    const int* __restrict__ pos_index, const float* __restrict__ pos_enc,
    const float* __restrict__ zWe1, const float* __restrict__ be1,
    const float* __restrict__ W0, const float* __restrict__ b0,
    ushort16* __restrict__ hb)
{
    int wid = threadIdx.x >> 6;
    int lane = threadIdx.x & 63;
    float be = be1[0];
    float2 w2 = ((const float2*)W0)[lane];
    float2 b2 = ((const float2*)b0)[lane];
    for (int n = blockIdx.x * 4 + wid; n < cN; n += gridDim.x * 4) {
        int e0 = rowptr[n], e1 = rowptr[n + 1];
        float part = 0.f;
        for (int i = e0 + lane; i < e1; i += 64) {
            int4 r = erec[i];
            float a = zcalc1(r, zWe1, pos_index, pos_enc);
            part += fmaxf(1.f + a + be, 0.f);
        }
        #pragma unroll
        for (int off = 32; off > 0; off >>= 1)
            part += __shfl_xor(part, off);
        float h0 = 1.f + part;
        float ox = eluf(h0 * w2.x + b2.x);
        float oy = eluf(h0 * w2.y + b2.y);
        ((uint32*)hb)[(size_t)n * 64 + lane] = f2bf2pack(ox, oy);
    }
}

// ===== convs edge phase: half-wave pairing, 12 edges/iter (6 per half) =====
// lanes 0-31 take even-offset edges, 32-63 odd-offset edges of the SAME node;
// cross-half combine via shfl_xor(32). hb[n] = bf16(x[n] + sum relu(...)).
__global__ __launch_bounds__(256) void convs_gather(
    const int* __restrict__ rowptr, const int4* __restrict__ erec,
    const int* __restrict__ pos_index, const float* __restrict__ pos_enc,
    const ushort16* __restrict__ zWe,
    const float* __restrict__ be,
    const float* __restrict__ x,       // fp32 self term
    const ushort16* __restrict__ xb,   // bf16 gather operand
    ushort16* __restrict__ hb)
{
    int wid = threadIdx.x >> 6;
    int lane = threadIdx.x & 63;
    int h  = lane >> 5;       // half id (0: even edges, 1: odd edges)
    int l5 = lane & 31;       // lane within half -> channels 4*l5..4*l5+3
    float4 b4 = ((const float4*)be)[l5];
    for (int n = blockIdx.x * 4 + wid; n < cN; n += gridDim.x * 4) {
        int e0 = rowptr[n], e1 = rowptr[n + 1];
        // hoist independent self-term load: hides under the whole edge loop
        float4 xn = ((const float4*)(x + (size_t)n * HID))[l5];
        float4 acc = make_float4(0.f, 0.f, 0.f, 0.f);
        int i = e0;
        // 12 edges/iter: each half takes 6 (unrolled) -> 12 load chains in flight
        for (; i + 12 <= e1; i += 12) {
            int4 r0 = erec[i + h];
            int4 r1 = erec[i + 2 + h];
            int4 r2 = erec[i + 4 + h];
            int4 r3 = erec[i + 6 + h];
            int4 r4 = erec[i + 8 + h];
            int4 r5 = erec[i + 10 + h];
            uint2 x0 = ((const uint2*)(xb + (size_t)r0.x * HID))[l5];
            uint2 x1 = ((const uint2*)(xb + (size_t)r1.x * HID))[l5];
            uint2 x2 = ((const uint2*)(xb + (size_t)r2.x * HID))[l5];
            uint2 x3 = ((const uint2*)(xb + (size_t)r3.x * HID))[l5];
            uint2 x4 = ((const uint2*)(xb + (size_t)r4.x * HID))[l5];
            uint2 x5 = ((const uint2*)(xb + (size_t)r5.x * HID))[l5];
            edge_acc(r0, x0, l5, zWe, pos_index, pos_enc, b4, acc);
            edge_acc(r1, x1, l5, zWe, pos_index, pos_enc, b4, acc);
            edge_acc(r2, x2, l5, zWe, pos_index, pos_enc, b4, acc);
            edge_acc(r3, x3, l5, zWe, pos_index, pos_enc, b4, acc);
            edge_acc(r4, x4, l5, zWe, pos_index, pos_enc, b4, acc);
            edge_acc(r5, x5, l5, zWe, pos_index, pos_enc, b4, acc);
        }
        // 8 edges: 4 per half
        if (i + 8 <= e1) {
            int4 r0 = erec[i + h];
            int4 r1 = erec[i + 2 + h];
            int4 r2 = erec[i + 4 + h];
            int4 r3 = erec[i + 6 + h];
            uint2 x0 = ((const uint2*)(xb + (size_t)r0.x * HID))[l5];
            uint2 x1 = ((const uint2*)(xb + (size_t)r1.x * HID))[l5];
            uint2 x2 = ((const uint2*)(xb + (size_t)r2.x * HID))[l5];
            uint2 x3 = ((const uint2*)(xb + (size_t)r3.x * HID))[l5];
            edge_acc(r0, x0, l5, zWe, pos_index, pos_enc, b4, acc);
            edge_acc(r1, x1, l5, zWe, pos_index, pos_enc, b4, acc);
            edge_acc(r2, x2, l5, zWe, pos_index, pos_enc, b4, acc);
            edge_acc(r3, x3, l5, zWe, pos_index, pos_enc, b4, acc);
            i += 8;
        }
        // 4 edges: 2 per half
        if (i + 4 <= e1) {
            int4 r0 = erec[i + h];
            int4 r1 = erec[i + 2 + h];
            uint2 x0 = ((const uint2*)(xb + (size_t)r0.x * HID))[l5];
            uint2 x1 = ((const uint2*)(xb + (size_t)r1.x * HID))[l5];
            edge_acc(r0, x0, l5, zWe, pos_index, pos_enc, b4, acc);
            edge_acc(r1, x1, l5, zWe, pos_index, pos_enc, b4, acc);
            i += 4;
        }
        // 2 edges: 1 per half
        if (i + 2 <= e1) {
            int4 r0 = erec[i + h];
            uint2 x0 = ((const uint2*)(xb + (size_t)r0.x * HID))[l5];
            edge_acc(r0, x0, l5, zWe, pos_index, pos_enc, b4, acc);
            i += 2;
        }
        // final odd edge: half A only
        if (i < e1 && h == 0) {
            int4 r0 = erec[i];
            uint2 x0 = ((const uint2*)(xb + (size_t)r0.x * HID))[l5];
            edge_acc(r0, x0, l5, zWe, pos_index, pos_enc, b4, acc);
        }
        // combine halves (partner lane holds same channels)
        acc.x += __shfl_xor(acc.x, 32);
        acc.y += __shfl_xor(acc.y, 32);
        acc.z += __shfl_xor(acc.z, 32);
        acc.w += __shfl_xor(acc.w, 32);
        if (h == 0) {
            uint2 pk;
            pk.x = f2bf2pack(xn.x + acc.x, xn.y + acc.y);
            pk.y = f2bf2pack(xn.z + acc.z, xn.w + acc.w);
            ((uint2*)(hb + (size_t)n * HID))[l5] = pk;
        }
    }
}

// ---- swapped-operand MFMA matmul: y = elu(Xb @ W + b) ----
__global__ __launch_bounds__(256) void node_mm_mfma(
    const ushort16* __restrict__ Xb, const ushort16* __restrict__ Wt,
    const float* __restrict__ b,
    float* __restrict__ Y, ushort16* __restrict__ Yb, int M)
{
    int wv = threadIdx.x >> 6;
    int lane = threadIdx.x & 63;
    int row0 = blockIdx.x * 64 + wv * 16;
    int r = lane & 15;
    int g = lane >> 4;
    int grow = row0 + r;
    bf16x8s zero8 = {0, 0, 0, 0, 0, 0, 0, 0};
    bf16x8s xf[4];
    #pragma unroll
    for (int kk = 0; kk < 4; ++kk)
        xf[kk] = (grow < M) ? *(const bf16x8s*)(Xb + (size_t)grow * HID + kk * 32 + g * 8)
                            : zero8;
    f32x4 acc[8];
    #pragma unroll
    for (int ct = 0; ct < 8; ++ct) acc[ct] = (f32x4){0.f, 0.f, 0.f, 0.f};
    #pragma unroll
    for (int kk = 0; kk < 4; ++kk) {
        #pragma unroll
        for (int ct = 0; ct < 8; ++ct) {
            bf16x8s wf = *(const bf16x8s*)(Wt + (size_t)(ct * 16 + r) * HID + kk * 32 + g * 8);
            acc[ct] = __builtin_amdgcn_mfma_f32_16x16x32_bf16(wf, xf[kk], acc[ct], 0, 0, 0);
        }
    }
    if (grow < M) {
        #pragma unroll
        for (int ct = 0; ct < 8; ++ct) {
            int c0 = ct * 16 + g * 4;
            float4 bv = *(const float4*)(b + c0);
            float4 o;
            o.x = eluf(acc[ct][0] + bv.x);
            o.y = eluf(acc[ct][1] + bv.y);
            o.z = eluf(acc[ct][2] + bv.z);
            o.w = eluf(acc[ct][3] + bv.w);
            *(float4*)(Y + (size_t)grow * HID + c0) = o;
            if (Yb) {
                uint2 pk;
                pk.x = f2bf2pack(o.x, o.y);
                pk.y = f2bf2pack(o.z, o.w);
                *(uint2*)(Yb + (size_t)grow * HID + c0) = pk;
            }
        }
    }
}

// ---- fused double MFMA matmul: y = elu(elu(Xb@WA+bA)@WB+bB) ----
__global__ __launch_bounds__(256) void node_mm2_mfma(
    const ushort16* __restrict__ Xb,
    const ushort16* __restrict__ WtA, const float* __restrict__ bA,
    const ushort16* __restrict__ WtB, const float* __restrict__ bB,
    float* __restrict__ Y, ushort16* __restrict__ Yb, int M)
{
    __shared__ float4 TsV[1024];       // 16 KB: 64 rows x 256 B, swizzled
    char* Ts = (char*)TsV;
    int wv = threadIdx.x >> 6;
    int lane = threadIdx.x & 63;
    int row0 = blockIdx.x * 64 + wv * 16;
    int r = lane & 15;
    int g = lane >> 4;
    int grow = row0 + r;
    int rowL = wv * 16 + r;
    bf16x8s zero8 = {0, 0, 0, 0, 0, 0, 0, 0};
    bf16x8s xf[4];
    #pragma unroll
    for (int kk = 0; kk < 4; ++kk)
        xf[kk] = (grow < M) ? *(const bf16x8s*)(Xb + (size_t)grow * HID + kk * 32 + g * 8)
                            : zero8;
    f32x4 acc[8];
    #pragma unroll
    for (int ct = 0; ct < 8; ++ct) acc[ct] = (f32x4){0.f, 0.f, 0.f, 0.f};
    #pragma unroll
    for (int kk = 0; kk < 4; ++kk) {
        #pragma unroll
        for (int ct = 0; ct < 8; ++ct) {
            bf16x8s wf = *(const bf16x8s*)(WtA + (size_t)(ct * 16 + r) * HID + kk * 32 + g * 8);
            acc[ct] = __builtin_amdgcn_mfma_f32_16x16x32_bf16(wf, xf[kk], acc[ct], 0, 0, 0);
        }
    }
    #pragma unroll
    for (int ct = 0; ct < 8; ++ct) {
        int c0 = ct * 16 + g * 4;
        float4 bv = *(const float4*)(bA + c0);
        uint2 pk;
        pk.x = f2bf2pack(eluf(acc[ct][0] + bv.x), eluf(acc[ct][1] + bv.y));
        pk.y = f2bf2pack(eluf(acc[ct][2] + bv.z), eluf(acc[ct][3] + bv.w));
        int boff = (c0 * 2) ^ ((rowL & 7) << 4);
        *(uint2*)(Ts + rowL * 256 + boff) = pk;
    }
    bf16x8s tf[4];
    #pragma unroll
    for (int kk = 0; kk < 4; ++kk) {
        int boff = (kk * 64 + g * 16) ^ ((rowL & 7) << 4);
        tf[kk] = *(const bf16x8s*)(Ts + rowL * 256 + boff);
    }
    #pragma unroll
    for (int ct = 0; ct < 8; ++ct) acc[ct] = (f32x4){0.f, 0.f, 0.f, 0.f};
    #pragma unroll
    for (int kk = 0; kk < 4; ++kk) {
        #pragma unroll
        for (int ct = 0; ct < 8; ++ct) {
            bf16x8s wf = *(const bf16x8s*)(WtB + (size_t)(ct * 16 + r) * HID + kk * 32 + g * 8);
            acc[ct] = __builtin_amdgcn_mfma_f32_16x16x32_bf16(wf, tf[kk], acc[ct], 0, 0, 0);
        }
    }
    if (grow < M) {
        #pragma unroll
        for (int ct = 0; ct < 8; ++ct) {
            int c0 = ct * 16 + g * 4;
            float4 bv = *(const float4*)(bB + c0);
            float4 o;
            o.x = eluf(acc[ct][0] + bv.x);
            o.y = eluf(acc[ct][1] + bv.y);
            o.z = eluf(acc[ct][2] + bv.z);
            o.w = eluf(acc[ct][3] + bv.w);
            *(float4*)(Y + (size_t)grow * HID + c0) = o;
            if (Yb) {
                uint2 pk;
                pk.x = f2bf2pack(o.x, o.y);
                pk.y = f2bf2pack(o.z, o.w);
                *(uint2*)(Yb + (size_t)grow * HID + c0) = pk;
            }
        }
    }
}

// ---- fused pool + head, 512 threads: 4-way node split + k-split matvec ----
__global__ __launch_bounds__(512) void pool_head(
    const float* __restrict__ x, const int* __restrict__ gs,
    const float* __restrict__ W1, const float* __restrict__ b1,
    const float* __restrict__ W2, const float* __restrict__ b2,
    float* __restrict__ out) {
    __shared__ float red[4][HID];
    __shared__ float ps[HID];
    __shared__ float hs[HID];
    int g = blockIdx.x, t = threadIdx.x;
    int part = t >> 7, ch = t & 127;
    int n0 = gs[g], n1 = gs[g + 1];
    float acc = 0.f;
    for (int n = n0 + part; n < n1; n += 4) acc += x[(size_t)n * HID + ch];
    red[part][ch] = acc;
    __syncthreads();
    if (part == 0) ps[ch] = red[0][ch] + red[1][ch] + red[2][ch] + red[3][ch];
    __syncthreads();
    float a = 0.f;
    #pragma unroll 8
    for (int k = part * 32; k < part * 32 + 32; ++k) a += ps[k] * W1[k * HID + ch];
    red[part][ch] = a;
    __syncthreads();
    if (part == 0)
        hs[ch] = eluf(red[0][ch] + red[1][ch] + red[2][ch] + red[3][ch] + b1[ch]);
    __syncthreads();
    if (t < 10) {
        float o = b2[t];
        #pragma unroll 8
        for (int k = 0; k < HID; ++k) o += hs[k] * W2[k * 10 + t];
        out[(size_t)g * 10 + t] = o;
    }
}

extern "C" void kernel_launch(void* const* d_in, const int* in_sizes, int n_in,
                              void* d_out, int out_size, void* d_ws, size_t ws_size,
                              hipStream_t stream) {
    const int*   ei        = (const int*)d_in[0];   // [2][E]
    const int*   batch     = (const int*)d_in[1];   // [N]
    const int*   pos_index = (const int*)d_in[2];   // [P]
    const float* pos_enc   = (const float*)d_in[3]; // [P]
    const int*   pos_batch = (const int*)d_in[4];   // [P]
    const float* z         = (const float*)d_in[5]; // [ZV][H]
    const float* c1W0      = (const float*)d_in[6]; // [1][H]
    const float* c1b0      = (const float*)d_in[7];
    const float* c1W1      = (const float*)d_in[8]; // [H][H]
    const float* c1b1      = (const float*)d_in[9];
    const float* c1We      = (const float*)d_in[10]; // [H][1]
    const float* c1be      = (const float*)d_in[11]; // [1]
    const float* cW0       = (const float*)d_in[12]; // [3][H][H]
    const float* cb0       = (const float*)d_in[13];
    const float* cW1       = (const float*)d_in[14];
    const float* cb1       = (const float*)d_in[15];
    const float* cWe       = (const float*)d_in[16]; // [3][H][H]
    const float* cbe       = (const float*)d_in[17]; // [3][H]
    const float* l1W       = (const float*)d_in[18];
    const float* l1b       = (const float*)d_in[19];
    const float* l2W       = (const float*)d_in[20];
    const float* l2b       = (const float*)d_in[21];
    float* out = (float*)d_out;

    const int* src = ei;
    const int* dst = ei + cE;

    char* ws = (char*)d_ws;
    size_t off = 0;
    auto alloc = [&](size_t bytes) -> void* {
        void* p = ws + off;
        off += (bytes + 511) & ~(size_t)511;
        return p;
    };
    ushort16* zWe3  = (ushort16*)alloc((size_t)3 * cZV * HID * 2);
    float* zWe1     = (float*)alloc((size_t)cZV * 4);
    ushort16* Wt    = (ushort16*)alloc((size_t)10 * HID * HID * 2);
    ushort16* zb    = (ushort16*)alloc((size_t)cZV * HID * 2);
    int*   eps      = (int*)  alloc((size_t)(cE + 1) * 4);
    float* x        = (float*)alloc((size_t)cN * HID * 4);
    ushort16* xbf   = (ushort16*)alloc((size_t)cN * HID * 2);
    ushort16* hbf   = (ushort16*)alloc((size_t)cN * HID * 2);
    int*   deg      = (int*)  alloc((size_t)cN * 4);
    int*   rowptr   = (int*)  alloc((size_t)(cN + 1) * 4);
    int*   cursor   = (int*)  alloc((size_t)(cN + 1) * 4);
    int*   csr_eid  = (int*)  alloc((size_t)cE * 4);
    int4*  erec     = (int4*) alloc((size_t)cE * 16);
    int*   bsum     = (int*)  alloc((size_t)NB * 4);
    int*   boffs    = (int*)  alloc((size_t)NB * 4);
    int*   gs       = (int*)  alloc((size_t)(cG + 1) * 4);

    // prep: eps + deg + gs + z->bf16 + zWe1, then weight tables
    hipMemsetAsync(deg, 0, (size_t)cN * 4, stream);
    prep_kernel<<<(cP + 255) / 256, 256, 0, stream>>>(pos_batch, batch, dst, z, c1We,
                                                      eps, gs, deg, zb, zWe1);
    wt_kernel<<<10, 256, 0, stream>>>(c1W1, cW0, cW1, cWe, Wt);
    zwe_mfma<<<dim3((cZV + 63) / 64, 3), 256, 0, stream>>>(zb, Wt + (size_t)7 * HID * HID,
                                                           zWe3);

    // CSR build (dst fixed across layers)
    scan1<<<NB, 512, 0, stream>>>(deg, rowptr, bsum);
    scan2<<<1, 128, 0, stream>>>(bsum, boffs);
    scan3<<<(cN + 255) / 256, 256, 0, stream>>>(rowptr, cursor, boffs);
    csr_scatter<<<(cE + 255) / 256, 256, 0, stream>>>(dst, cursor, csr_eid);
    csr_sort_erec_wave<<<(cN + 3) / 4, 256, 0, stream>>>(rowptr, csr_eid, src, eps,
                                                         pos_index, pos_enc, erec);

    // conv1: gather -> hbf, then single MFMA matmul -> x fp32 + xbf
    conv1_gather<<<GATHER_BLOCKS, 256, 0, stream>>>(rowptr, erec, pos_index, pos_enc,
                                                    zWe1, c1be, c1W0, c1b0, hbf);
    node_mm_mfma<<<(cN + 63) / 64, 256, 0, stream>>>(hbf, Wt, c1b1, x, xbf, cN);

    // convs 0..2: gather -> hbf; fused W0+W1 MFMA -> x (+xbf)
    for (int l = 0; l < 3; ++l) {
        convs_gather<<<GATHER_BLOCKS, 256, 0, stream>>>(rowptr, erec, pos_index, pos_enc,
                                                        zWe3 + (size_t)l * cZV * HID,
                                                        cbe + (size_t)l * HID, x, xbf, hbf);
        node_mm2_mfma<<<(cN + 63) / 64, 256, 0, stream>>>(
            hbf,
            Wt + (size_t)(1 + l) * HID * HID, cb0 + (size_t)l * HID,
            Wt + (size_t)(4 + l) * HID * HID, cb1 + (size_t)l * HID,
            x, (l < 2) ? xbf : nullptr, cN);
    }

    // pool + head
    pool_head<<<cG, 512, 0, stream>>>(x, gs, l1W, l1b, l2W, l2b, out);
}

// Round 14
// 561.001 us; speedup vs baseline: 1.0460x; 1.0460x over previous
//
#include <hip/hip_runtime.h>
#include <hip/hip_bf16.h>
#include <math.h>

#define HID 128
constexpr int cN  = 50000;   // nodes
constexpr int cE  = 600000;  // edges
constexpr int cG  = 512;     // graphs
constexpr int cZV = 1800;    // z vocab
constexpr int cP  = 600000;  // positions
constexpr int NB  = (cN + 511) / 512;   // scan blocks = 98
constexpr int GATHER_BLOCKS = 2048;     // 8 blocks/CU x 256 CU

typedef unsigned int uint32;
typedef unsigned short ushort16;
typedef __attribute__((ext_vector_type(8))) short bf16x8s;
typedef __attribute__((ext_vector_type(4))) float f32x4;

__device__ __forceinline__ float eluf(float v) {
    return v > 0.f ? v : (__expf(v) - 1.f);
}

__device__ __forceinline__ float2 bf2f2(uint32 u) {
    float2 r;
    r.x = __uint_as_float(u << 16);
    r.y = __uint_as_float(u & 0xffff0000u);
    return r;
}

__device__ __forceinline__ ushort16 f2bf(float f) {
    uint32 u = __float_as_uint(f);
    u += 0x7fffu + ((u >> 16) & 1u);
    return (ushort16)(u >> 16);
}

__device__ __forceinline__ uint32 f2bf2pack(float a, float b) {
    return (uint32)f2bf(a) | ((uint32)f2bf(b) << 16);
}

// ---- fused prep: eps, deg histogram, graph starts, z->bf16, zWe1 dot,
// ----             Wt transpose+cast (m=0 c1W1; 1..3 cW0; 4..6 cW1; 7..9 cWe)
__global__ void prep_kernel(const int* __restrict__ pos_batch, const int* __restrict__ batch,
                            const int* __restrict__ dst, const float* __restrict__ z,
                            const float* __restrict__ We1,
                            const float* __restrict__ c1W1, const float* __restrict__ cW0,
                            const float* __restrict__ cW1, const float* __restrict__ cWe,
                            int* __restrict__ eps, int* __restrict__ gs,
                            int* __restrict__ deg, ushort16* __restrict__ zb,
                            float* __restrict__ zWe1, ushort16* __restrict__ Wt) {
    int i = blockIdx.x * blockDim.x + threadIdx.x;
    if (i < cP) {
        int cur = pos_batch[i];
        int prev = (i == 0) ? -1 : pos_batch[i - 1];
        for (int e = prev + 1; e <= cur; ++e) eps[e] = i;
        if (i == cP - 1)
            for (int e = cur + 1; e <= cE; ++e) eps[e] = cP;
    }
    if (i < cE) atomicAdd(&deg[dst[i]], 1);
    if (i < cZV * HID) zb[i] = f2bf(z[i]);
    if (i < cZV) {
        float acc = 0.f;
        #pragma unroll 8
        for (int k = 0; k < HID; ++k) acc += z[i * HID + k] * We1[k];
        zWe1[i] = acc;
    }
    if (i < 10 * HID * HID) {
        int m = i >> 14;            // / (128*128)
        int idx = i & (HID * HID - 1);
        const float* srcp = (m == 0) ? c1W1
                          : (m <= 3) ? (cW0 + (size_t)(m - 1) * HID * HID)
                          : (m <= 6) ? (cW1 + (size_t)(m - 4) * HID * HID)
                                     : (cWe + (size_t)(m - 7) * HID * HID);
        int c = idx >> 7, k = idx & 127;
        Wt[(size_t)m * HID * HID + idx] = f2bf(srcp[(size_t)k * HID + c]);
    }
    if (i <= cG) {
        int lo = 0, hi = cN;
        while (lo < hi) {
            int mid = (lo + hi) >> 1;
            if (batch[mid] < i) lo = mid + 1; else hi = mid;
        }
        gs[i] = lo;
    }
}

// ---- MFMA zWe tables: zWe[l][v][:] = bf16( zb[v][:] @ We[l] ) ----
__global__ __launch_bounds__(256) void zwe_mfma(
    const ushort16* __restrict__ zb,    // [cZV][128] bf16
    const ushort16* __restrict__ WtE,   // [3][128][128] bf16 transposed
    ushort16* __restrict__ zWeb)        // [3][cZV][128] bf16
{
    int l = blockIdx.y;
    const ushort16* Wt = WtE + (size_t)l * HID * HID;
    ushort16* outp = zWeb + (size_t)l * cZV * HID;
    int wv = threadIdx.x >> 6;
    int lane = threadIdx.x & 63;
    int row0 = blockIdx.x * 64 + wv * 16;
    int r = lane & 15;
    int g = lane >> 4;
    int grow = row0 + r;
    bf16x8s zero8 = {0, 0, 0, 0, 0, 0, 0, 0};
    bf16x8s xf[4];
    #pragma unroll
    for (int kk = 0; kk < 4; ++kk)
        xf[kk] = (grow < cZV) ? *(const bf16x8s*)(zb + (size_t)grow * HID + kk * 32 + g * 8)
                              : zero8;
    f32x4 acc[8];
    #pragma unroll
    for (int ct = 0; ct < 8; ++ct) acc[ct] = (f32x4){0.f, 0.f, 0.f, 0.f};
    #pragma unroll
    for (int kk = 0; kk < 4; ++kk) {
        #pragma unroll
        for (int ct = 0; ct < 8; ++ct) {
            bf16x8s wf = *(const bf16x8s*)(Wt + (size_t)(ct * 16 + r) * HID + kk * 32 + g * 8);
            acc[ct] = __builtin_amdgcn_mfma_f32_16x16x32_bf16(wf, xf[kk], acc[ct], 0, 0, 0);
        }
    }
    if (grow < cZV) {
        #pragma unroll
        for (int ct = 0; ct < 8; ++ct) {
            int c0 = ct * 16 + g * 4;
            uint2 pk;
            pk.x = f2bf2pack(acc[ct][0], acc[ct][1]);
            pk.y = f2bf2pack(acc[ct][2], acc[ct][3]);
            *(uint2*)(outp + (size_t)grow * HID + c0) = pk;
        }
    }
}

// ======================= CSR scan chain =======================
__global__ void scan1(const int* __restrict__ deg, int* __restrict__ rowptr,
                      int* __restrict__ bsum) {
    __shared__ int t[512];
    int i = blockIdx.x * 512 + threadIdx.x;
    int v = (i < cN) ? deg[i] : 0;
    t[threadIdx.x] = v;
    __syncthreads();
    for (int off = 1; off < 512; off <<= 1) {
        int add = (threadIdx.x >= off) ? t[threadIdx.x - off] : 0;
        __syncthreads();
        t[threadIdx.x] += add;
        __syncthreads();
    }
    if (i < cN) rowptr[i + 1] = t[threadIdx.x];
    if (threadIdx.x == 511) bsum[blockIdx.x] = t[511];
}

__global__ void scan2(const int* __restrict__ bsum, int* __restrict__ boffs) {
    __shared__ int t[128];
    int i = threadIdx.x;
    int v = (i < NB) ? bsum[i] : 0;
    t[i] = v;
    __syncthreads();
    for (int off = 1; off < 128; off <<= 1) {
        int add = (i >= off) ? t[i - off] : 0;
        __syncthreads();
        t[i] += add;
        __syncthreads();
    }
    if (i < NB) boffs[i] = t[i] - v;   // exclusive prefix
}

__global__ void scan3(int* __restrict__ rowptr, int* __restrict__ cursor,
                      const int* __restrict__ boffs) {
    int i = blockIdx.x * blockDim.x + threadIdx.x;
    if (i == 0) { rowptr[0] = 0; cursor[0] = 0; }
    if (i < cN) {
        int val = rowptr[i + 1] + boffs[i >> 9];
        rowptr[i + 1] = val;
        cursor[i + 1] = val;
    }
}

__global__ void csr_scatter(const int* __restrict__ dst, int* __restrict__ cursor,
                            int* __restrict__ csr_eid) {
    int e = blockIdx.x * blockDim.x + threadIdx.x;
    if (e >= cE) return;
    int p = atomicAdd(&cursor[dst[e]], 1);
    csr_eid[p] = e;
}

// ---- wave-parallel deterministic sort (bitonic over 64 lanes) + erec build ----
// erec[i] = (src, cnt | (pstart<<8), pidx0, bits(penc0))
__device__ __forceinline__ int4 make_erec(int e, const int* __restrict__ src,
                                          const int* __restrict__ eps,
                                          const int* __restrict__ pos_index,
                                          const float* __restrict__ pos_enc) {
    int s = eps[e], t = eps[e + 1];
    int cnt = t - s;
    int4 r;
    r.x = src[e];
    r.y = cnt | (s << 8);
    if (cnt >= 1) { r.z = pos_index[s]; r.w = __float_as_int(pos_enc[s]); }
    else          { r.z = 0;            r.w = 0; }
    return r;
}

__global__ __launch_bounds__(256) void csr_sort_erec_wave(
    const int* __restrict__ rowptr, int* __restrict__ eid,
    const int* __restrict__ src, const int* __restrict__ eps,
    const int* __restrict__ pos_index, const float* __restrict__ pos_enc,
    int4* __restrict__ erec)
{
    int wid = threadIdx.x >> 6;
    int lane = threadIdx.x & 63;
    int n = blockIdx.x * 4 + wid;
    if (n >= cN) return;
    int a = rowptr[n], b = rowptr[n + 1];
    int d = b - a;
    if (d > 64) {
        if (lane == 0) {
            for (int i = a + 1; i < b; ++i) {
                int v = eid[i];
                int j = i - 1;
                while (j >= a && eid[j] > v) { eid[j + 1] = eid[j]; --j; }
                eid[j + 1] = v;
            }
            for (int i = a; i < b; ++i)
                erec[i] = make_erec(eid[i], src, eps, pos_index, pos_enc);
        }
        return;
    }
    int v = (lane < d) ? eid[a + lane] : 0x7fffffff;
    #pragma unroll
    for (int k = 2; k <= 64; k <<= 1) {
        for (int j = k >> 1; j > 0; j >>= 1) {
            int w = __shfl_xor(v, j);
            bool up    = ((lane & k) == 0);
            bool lower = ((lane & j) == 0);
            v = (up == lower) ? min(v, w) : max(v, w);
        }
    }
    if (lane < d)
        erec[a + lane] = make_erec(v, src, eps, pos_index, pos_enc);
}

// ---- per-edge z contribution, 4 channels/lane (half-wave layout) ----
__device__ __forceinline__ float4 zcalc4(int4 r, int l5,
                                         const ushort16* __restrict__ zWe,
                                         const int* __restrict__ pos_index,
                                         const float* __restrict__ pos_enc) {
    float w = __int_as_float(r.w);
    uint2 zu = ((const uint2*)(zWe + (size_t)r.z * HID))[l5];
    float2 za = bf2f2(zu.x), zc = bf2f2(zu.y);
    float4 z;
    z.x = w * za.x; z.y = w * za.y; z.z = w * zc.x; z.w = w * zc.y;
    int cnt = r.y & 255;
    if (cnt >= 2) {
        int s = ((uint32)r.y) >> 8;
        for (int p = s + 1; p < s + cnt; ++p) {
            float wp = pos_enc[p];
            uint2 zp = ((const uint2*)(zWe + (size_t)pos_index[p] * HID))[l5];
            float2 pa = bf2f2(zp.x), pb = bf2f2(zp.y);
            z.x += wp * pa.x; z.y += wp * pa.y; z.z += wp * pb.x; z.w += wp * pb.y;
        }
    }
    return z;
}

__device__ __forceinline__ float zcalc1(int4 r,
                                        const float* __restrict__ zWe1,
                                        const int* __restrict__ pos_index,
                                        const float* __restrict__ pos_enc) {
    float a = __int_as_float(r.w) * zWe1[r.z];
    int cnt = r.y & 255;
    if (cnt >= 2) {
        int s = ((uint32)r.y) >> 8;
        for (int p = s + 1; p < s + cnt; ++p)
            a += pos_enc[p] * zWe1[pos_index[p]];
    }
    return a;
}

// fold one edge (4 channels/lane) into acc
__device__ __forceinline__ void edge_acc(int4 r, uint2 xu, int l5,
                                         const ushort16* __restrict__ zWe,
                                         const int* __restrict__ pos_index,
                                         const float* __restrict__ pos_enc,
                                         float4 b4, float4& acc) {
    float4 z = zcalc4(r, l5, zWe, pos_index, pos_enc);
    float2 xa = bf2f2(xu.x), xc = bf2f2(xu.y);
    acc.x += fmaxf(xa.x + z.x + b4.x, 0.f);
    acc.y += fmaxf(xa.y + z.y + b4.y, 0.f);
    acc.z += fmaxf(xc.x + z.z + b4.z, 0.f);
    acc.w += fmaxf(xc.y + z.w + b4.w, 0.f);
}

// ======================= conv1 (gather, grid-stride, fused node stage A) ============
__global__ __launch_bounds__(256) void conv1_gather(
    const int* __restrict__ rowptr, const int4* __restrict__ erec,
    const int* __restrict__ pos_index, const float* __restrict__ pos_enc,
    const float* __restrict__ zWe1, const float* __restrict__ be1,
    const float* __restrict__ W0, const float* __restrict__ b0,
    ushort16* __restrict__ hb)
{
    int wid = threadIdx.x >> 6;
    int lane = threadIdx.x & 63;
    float be = be1[0];
    float2 w2 = ((const float2*)W0)[lane];
    float2 b2 = ((const float2*)b0)[lane];
    for (int n = blockIdx.x * 4 + wid; n < cN; n += gridDim.x * 4) {
        int e0 = rowptr[n], e1 = rowptr[n + 1];
        float part = 0.f;
        for (int i = e0 + lane; i < e1; i += 64) {
            int4 r = erec[i];
            float a = zcalc1(r, zWe1, pos_index, pos_enc);
            part += fmaxf(1.f + a + be, 0.f);
        }
        #pragma unroll
        for (int off = 32; off > 0; off >>= 1)
            part += __shfl_xor(part, off);
        float h0 = 1.f + part;
        float ox = eluf(h0 * w2.x + b2.x);
        float oy = eluf(h0 * w2.y + b2.y);
        ((uint32*)hb)[(size_t)n * 64 + lane] = f2bf2pack(ox, oy);
    }
}

// ===== convs edge phase: half-wave edge pairing, 8 edges/iter, 4 ch/lane =====
// lanes 0-31 take even-offset edges, 32-63 odd-offset edges of the SAME node;
// cross-half combine via shfl_xor(32). hb[n] = bf16(x[n] + sum relu(...)).
__global__ __launch_bounds__(256) void convs_gather(
    const int* __restrict__ rowptr, const int4* __restrict__ erec,
    const int* __restrict__ pos_index, const float* __restrict__ pos_enc,
    const ushort16* __restrict__ zWe,
    const float* __restrict__ be,
    const float* __restrict__ x,       // fp32 self term
    const ushort16* __restrict__ xb,   // bf16 gather operand
    ushort16* __restrict__ hb)
{
    int wid = threadIdx.x >> 6;
    int lane = threadIdx.x & 63;
    int h  = lane >> 5;       // half id (0: even edges, 1: odd edges)
    int l5 = lane & 31;       // lane within half -> channels 4*l5..4*l5+3
    float4 b4 = ((const float4*)be)[l5];
    for (int n = blockIdx.x * 4 + wid; n < cN; n += gridDim.x * 4) {
        int e0 = rowptr[n], e1 = rowptr[n + 1];
        // hoisted independent self-term load: latency hides under the edge loop
        float4 xn = ((const float4*)(x + (size_t)n * HID))[l5];
        float4 acc = make_float4(0.f, 0.f, 0.f, 0.f);
        int i = e0;
        // 8 edges/iter: each half takes 4 (unrolled) -> 8 load chains in flight
        for (; i + 8 <= e1; i += 8) {
            int4 r0 = erec[i + h];
            int4 r1 = erec[i + 2 + h];
            int4 r2 = erec[i + 4 + h];
            int4 r3 = erec[i + 6 + h];
            uint2 x0 = ((const uint2*)(xb + (size_t)r0.x * HID))[l5];
            uint2 x1 = ((const uint2*)(xb + (size_t)r1.x * HID))[l5];
            uint2 x2 = ((const uint2*)(xb + (size_t)r2.x * HID))[l5];
            uint2 x3 = ((const uint2*)(xb + (size_t)r3.x * HID))[l5];
            edge_acc(r0, x0, l5, zWe, pos_index, pos_enc, b4, acc);
            edge_acc(r1, x1, l5, zWe, pos_index, pos_enc, b4, acc);
            edge_acc(r2, x2, l5, zWe, pos_index, pos_enc, b4, acc);
            edge_acc(r3, x3, l5, zWe, pos_index, pos_enc, b4, acc);
        }
        // 4 edges: 2 per half
        if (i + 4 <= e1) {
            int4 r0 = erec[i + h];
            int4 r1 = erec[i + 2 + h];
            uint2 x0 = ((const uint2*)(xb + (size_t)r0.x * HID))[l5];
            uint2 x1 = ((const uint2*)(xb + (size_t)r1.x * HID))[l5];
            edge_acc(r0, x0, l5, zWe, pos_index, pos_enc, b4, acc);
            edge_acc(r1, x1, l5, zWe, pos_index, pos_enc, b4, acc);
            i += 4;
        }
        // 2 edges: 1 per half
        if (i + 2 <= e1) {
            int4 r0 = erec[i + h];
            uint2 x0 = ((const uint2*)(xb + (size_t)r0.x * HID))[l5];
            edge_acc(r0, x0, l5, zWe, pos_index, pos_enc, b4, acc);
            i += 2;
        }
        // final odd edge: half A only
        if (i < e1 && h == 0) {
            int4 r0 = erec[i];
            uint2 x0 = ((const uint2*)(xb + (size_t)r0.x * HID))[l5];
            edge_acc(r0, x0, l5, zWe, pos_index, pos_enc, b4, acc);
        }
        // combine halves (partner lane holds same channels)
        acc.x += __shfl_xor(acc.x, 32);
        acc.y += __shfl_xor(acc.y, 32);
        acc.z += __shfl_xor(acc.z, 32);
        acc.w += __shfl_xor(acc.w, 32);
        if (h == 0) {
            uint2 pk;
            pk.x = f2bf2pack(xn.x + acc.x, xn.y + acc.y);
            pk.y = f2bf2pack(xn.z + acc.z, xn.w + acc.w);
            ((uint2*)(hb + (size_t)n * HID))[l5] = pk;
        }
    }
}

// ---- swapped-operand MFMA matmul: y = elu(Xb @ W + b) ----
__global__ __launch_bounds__(256) void node_mm_mfma(
    const ushort16* __restrict__ Xb, const ushort16* __restrict__ Wt,
    const float* __restrict__ b,
    float* __restrict__ Y, ushort16* __restrict__ Yb, int M)
{
    int wv = threadIdx.x >> 6;
    int lane = threadIdx.x & 63;
    int row0 = blockIdx.x * 64 + wv * 16;
    int r = lane & 15;
    int g = lane >> 4;
    int grow = row0 + r;
    bf16x8s zero8 = {0, 0, 0, 0, 0, 0, 0, 0};
    bf16x8s xf[4];
    #pragma unroll
    for (int kk = 0; kk < 4; ++kk)
        xf[kk] = (grow < M) ? *(const bf16x8s*)(Xb + (size_t)grow * HID + kk * 32 + g * 8)
                            : zero8;
    f32x4 acc[8];
    #pragma unroll
    for (int ct = 0; ct < 8; ++ct) acc[ct] = (f32x4){0.f, 0.f, 0.f, 0.f};
    #pragma unroll
    for (int kk = 0; kk < 4; ++kk) {
        #pragma unroll
        for (int ct = 0; ct < 8; ++ct) {
            bf16x8s wf = *(const bf16x8s*)(Wt + (size_t)(ct * 16 + r) * HID + kk * 32 + g * 8);
            acc[ct] = __builtin_amdgcn_mfma_f32_16x16x32_bf16(wf, xf[kk], acc[ct], 0, 0, 0);
        }
    }
    if (grow < M) {
        #pragma unroll
        for (int ct = 0; ct < 8; ++ct) {
            int c0 = ct * 16 + g * 4;
            float4 bv = *(const float4*)(b + c0);
            float4 o;
            o.x = eluf(acc[ct][0] + bv.x);
            o.y = eluf(acc[ct][1] + bv.y);
            o.z = eluf(acc[ct][2] + bv.z);
            o.w = eluf(acc[ct][3] + bv.w);
            *(float4*)(Y + (size_t)grow * HID + c0) = o;
            if (Yb) {
                uint2 pk;
                pk.x = f2bf2pack(o.x, o.y);
                pk.y = f2bf2pack(o.z, o.w);
                *(uint2*)(Yb + (size_t)grow * HID + c0) = pk;
            }
        }
    }
}

// ---- fused double MFMA matmul: y = elu(elu(Xb@WA+bA)@WB+bB) ----
__global__ __launch_bounds__(256) void node_mm2_mfma(
    const ushort16* __restrict__ Xb,
    const ushort16* __restrict__ WtA, const float* __restrict__ bA,
    const ushort16* __restrict__ WtB, const float* __restrict__ bB,
    float* __restrict__ Y, ushort16* __restrict__ Yb, int M)
{
    __shared__ float4 TsV[1024];       // 16 KB: 64 rows x 256 B, swizzled
    char* Ts = (char*)TsV;
    int wv = threadIdx.x >> 6;
    int lane = threadIdx.x & 63;
    int row0 = blockIdx.x * 64 + wv * 16;
    int r = lane & 15;
    int g = lane >> 4;
    int grow = row0 + r;
    int rowL = wv * 16 + r;
    bf16x8s zero8 = {0, 0, 0, 0, 0, 0, 0, 0};
    bf16x8s xf[4];
    #pragma unroll
    for (int kk = 0; kk < 4; ++kk)
        xf[kk] = (grow < M) ? *(const bf16x8s*)(Xb + (size_t)grow * HID + kk * 32 + g * 8)
                            : zero8;
    f32x4 acc[8];
    #pragma unroll
    for (int ct = 0; ct < 8; ++ct) acc[ct] = (f32x4){0.f, 0.f, 0.f, 0.f};
    #pragma unroll
    for (int kk = 0; kk < 4; ++kk) {
        #pragma unroll
        for (int ct = 0; ct < 8; ++ct) {
            bf16x8s wf = *(const bf16x8s*)(WtA + (size_t)(ct * 16 + r) * HID + kk * 32 + g * 8);
            acc[ct] = __builtin_amdgcn_mfma_f32_16x16x32_bf16(wf, xf[kk], acc[ct], 0, 0, 0);
        }
    }
    #pragma unroll
    for (int ct = 0; ct < 8; ++ct) {
        int c0 = ct * 16 + g * 4;
        float4 bv = *(const float4*)(bA + c0);
        uint2 pk;
        pk.x = f2bf2pack(eluf(acc[ct][0] + bv.x), eluf(acc[ct][1] + bv.y));
        pk.y = f2bf2pack(eluf(acc[ct][2] + bv.z), eluf(acc[ct][3] + bv.w));
        int boff = (c0 * 2) ^ ((rowL & 7) << 4);
        *(uint2*)(Ts + rowL * 256 + boff) = pk;
    }
    bf16x8s tf[4];
    #pragma unroll
    for (int kk = 0; kk < 4; ++kk) {
        int boff = (kk * 64 + g * 16) ^ ((rowL & 7) << 4);
        tf[kk] = *(const bf16x8s*)(Ts + rowL * 256 + boff);
    }
    #pragma unroll
    for (int ct = 0; ct < 8; ++ct) acc[ct] = (f32x4){0.f, 0.f, 0.f, 0.f};
    #pragma unroll
    for (int kk = 0; kk < 4; ++kk) {
        #pragma unroll
        for (int ct = 0; ct < 8; ++ct) {
            bf16x8s wf = *(const bf16x8s*)(WtB + (size_t)(ct * 16 + r) * HID + kk * 32 + g * 8);
            acc[ct] = __builtin_amdgcn_mfma_f32_16x16x32_bf16(wf, tf[kk], acc[ct], 0, 0, 0);
        }
    }
    if (grow < M) {
        #pragma unroll
        for (int ct = 0; ct < 8; ++ct) {
            int c0 = ct * 16 + g * 4;
            float4 bv = *(const float4*)(bB + c0);
            float4 o;
            o.x = eluf(acc[ct][0] + bv.x);
            o.y = eluf(acc[ct][1] + bv.y);
            o.z = eluf(acc[ct][2] + bv.z);
            o.w = eluf(acc[ct][3] + bv.w);
            *(float4*)(Y + (size_t)grow * HID + c0) = o;
            if (Yb) {
                uint2 pk;
                pk.x = f2bf2pack(o.x, o.y);
                pk.y = f2bf2pack(o.z, o.w);
                *(uint2*)(Yb + (size_t)grow * HID + c0) = pk;
            }
        }
    }
}

// ---- fused pool + head, 512 threads: 4-way node split + k-split matvec ----
__global__ __launch_bounds__(512) void pool_head(
    const float* __restrict__ x, const int* __restrict__ gs,
    const float* __restrict__ W1, const float* __restrict__ b1,
    const float* __restrict__ W2, const float* __restrict__ b2,
    float* __restrict__ out) {
    __shared__ float red[4][HID];
    __shared__ float ps[HID];
    __shared__ float hs[HID];
    int g = blockIdx.x, t = threadIdx.x;
    int part = t >> 7, ch = t & 127;
    int n0 = gs[g], n1 = gs[g + 1];
    float acc = 0.f;
    for (int n = n0 + part; n < n1; n += 4) acc += x[(size_t)n * HID + ch];
    red[part][ch] = acc;
    __syncthreads();
    if (part == 0) ps[ch] = red[0][ch] + red[1][ch] + red[2][ch] + red[3][ch];
    __syncthreads();
    float a = 0.f;
    #pragma unroll 8
    for (int k = part * 32; k < part * 32 + 32; ++k) a += ps[k] * W1[k * HID + ch];
    red[part][ch] = a;
    __syncthreads();
    if (part == 0)
        hs[ch] = eluf(red[0][ch] + red[1][ch] + red[2][ch] + red[3][ch] + b1[ch]);
    __syncthreads();
    if (t < 10) {
        float o = b2[t];
        #pragma unroll 8
        for (int k = 0; k < HID; ++k) o += hs[k] * W2[k * 10 + t];
        out[(size_t)g * 10 + t] = o;
    }
}

extern "C" void kernel_launch(void* const* d_in, const int* in_sizes, int n_in,
                              void* d_out, int out_size, void* d_ws, size_t ws_size,
                              hipStream_t stream) {
    const int*   ei        = (const int*)d_in[0];   // [2][E]
    const int*   batch     = (const int*)d_in[1];   // [N]
    const int*   pos_index = (const int*)d_in[2];   // [P]
    const float* pos_enc   = (const float*)d_in[3]; // [P]
    const int*   pos_batch = (const int*)d_in[4];   // [P]
    const float* z         = (const float*)d_in[5]; // [ZV][H]
    const float* c1W0      = (const float*)d_in[6]; // [1][H]
    const float* c1b0      = (const float*)d_in[7];
    const float* c1W1      = (const float*)d_in[8]; // [H][H]
    const float* c1b1      = (const float*)d_in[9];
    const float* c1We      = (const float*)d_in[10]; // [H][1]
    const float* c1be      = (const float*)d_in[11]; // [1]
    const float* cW0       = (const float*)d_in[12]; // [3][H][H]
    const float* cb0       = (const float*)d_in[13];
    const float* cW1       = (const float*)d_in[14];
    const float* cb1       = (const float*)d_in[15];
    const float* cWe       = (const float*)d_in[16]; // [3][H][H]
    const float* cbe       = (const float*)d_in[17]; // [3][H]
    const float* l1W       = (const float*)d_in[18];
    const float* l1b       = (const float*)d_in[19];
    const float* l2W       = (const float*)d_in[20];
    const float* l2b       = (const float*)d_in[21];
    float* out = (float*)d_out;

    const int* src = ei;
    const int* dst = ei + cE;

    char* ws = (char*)d_ws;
    size_t off = 0;
    auto alloc = [&](size_t bytes) -> void* {
        void* p = ws + off;
        off += (bytes + 511) & ~(size_t)511;
        return p;
    };
    ushort16* zWe3  = (ushort16*)alloc((size_t)3 * cZV * HID * 2);
    float* zWe1     = (float*)alloc((size_t)cZV * 4);
    ushort16* Wt    = (ushort16*)alloc((size_t)10 * HID * HID * 2);
    ushort16* zb    = (ushort16*)alloc((size_t)cZV * HID * 2);
    int*   eps      = (int*)  alloc((size_t)(cE + 1) * 4);
    float* x        = (float*)alloc((size_t)cN * HID * 4);
    ushort16* xbf   = (ushort16*)alloc((size_t)cN * HID * 2);
    ushort16* hbf   = (ushort16*)alloc((size_t)cN * HID * 2);
    int*   deg      = (int*)  alloc((size_t)cN * 4);
    int*   rowptr   = (int*)  alloc((size_t)(cN + 1) * 4);
    int*   cursor   = (int*)  alloc((size_t)(cN + 1) * 4);
    int*   csr_eid  = (int*)  alloc((size_t)cE * 4);
    int4*  erec     = (int4*) alloc((size_t)cE * 16);
    int*   bsum     = (int*)  alloc((size_t)NB * 4);
    int*   boffs    = (int*)  alloc((size_t)NB * 4);
    int*   gs       = (int*)  alloc((size_t)(cG + 1) * 4);

    // prep: eps + deg + gs + z->bf16 + zWe1 + Wt (fused), then zWe tables
    hipMemsetAsync(deg, 0, (size_t)cN * 4, stream);
    prep_kernel<<<(cP + 255) / 256, 256, 0, stream>>>(pos_batch, batch, dst, z, c1We,
                                                      c1W1, cW0, cW1, cWe,
                                                      eps, gs, deg, zb, zWe1, Wt);
    zwe_mfma<<<dim3((cZV + 63) / 64, 3), 256, 0, stream>>>(zb, Wt + (size_t)7 * HID * HID,
                                                           zWe3);

    // CSR build (dst fixed across layers)
    scan1<<<NB, 512, 0, stream>>>(deg, rowptr, bsum);
    scan2<<<1, 128, 0, stream>>>(bsum, boffs);
    scan3<<<(cN + 255) / 256, 256, 0, stream>>>(rowptr, cursor, boffs);
    csr_scatter<<<(cE + 255) / 256, 256, 0, stream>>>(dst, cursor, csr_eid);
    csr_sort_erec_wave<<<(cN + 3) / 4, 256, 0, stream>>>(rowptr, csr_eid, src, eps,
                                                         pos_index, pos_enc, erec);

    // conv1: gather -> hbf, then single MFMA matmul -> x fp32 + xbf
    conv1_gather<<<GATHER_BLOCKS, 256, 0, stream>>>(rowptr, erec, pos_index, pos_enc,
                                                    zWe1, c1be, c1W0, c1b0, hbf);
    node_mm_mfma<<<(cN + 63) / 64, 256, 0, stream>>>(hbf, Wt, c1b1, x, xbf, cN);

    // convs 0..2: gather -> hbf; fused W0+W1 MFMA -> x (+xbf)
    for (int l = 0; l < 3; ++l) {
        convs_gather<<<GATHER_BLOCKS, 256, 0, stream>>>(rowptr, erec, pos_index, pos_enc,
                                                        zWe3 + (size_t)l * cZV * HID,
                                                        cbe + (size_t)l * HID, x, xbf, hbf);
        node_mm2_mfma<<<(cN + 63) / 64, 256, 0, stream>>>(
            hbf,
            Wt + (size_t)(1 + l) * HID * HID, cb0 + (size_t)l * HID,
            Wt + (size_t)(4 + l) * HID * HID, cb1 + (size_t)l * HID,
            x, (l < 2) ? xbf : nullptr, cN);
    }

    // pool + head
    pool_head<<<cG, 512, 0, stream>>>(x, gs, l1W, l1b, l2W, l2b, out);
}

// Round 15
// 502.055 us; speedup vs baseline: 1.1688x; 1.1174x over previous
//
#include <hip/hip_runtime.h>
#include <hip/hip_bf16.h>
#include <math.h>

#define HID 128
constexpr int cN  = 50000;   // nodes
constexpr int cE  = 600000;  // edges
constexpr int cG  = 512;     // graphs
constexpr int cZV = 1800;    // z vocab
constexpr int cP  = 600000;  // positions
constexpr int NB  = (cN + 511) / 512;   // scan blocks = 98
constexpr int GATHER_BLOCKS = 2048;     // 8 blocks/CU x 256 CU

typedef unsigned int uint32;
typedef unsigned short ushort16;
typedef __attribute__((ext_vector_type(8))) short bf16x8s;
typedef __attribute__((ext_vector_type(4))) float f32x4;

__device__ __forceinline__ float eluf(float v) {
    return v > 0.f ? v : (__expf(v) - 1.f);
}

__device__ __forceinline__ float2 bf2f2(uint32 u) {
    float2 r;
    r.x = __uint_as_float(u << 16);
    r.y = __uint_as_float(u & 0xffff0000u);
    return r;
}

__device__ __forceinline__ ushort16 f2bf(float f) {
    uint32 u = __float_as_uint(f);
    u += 0x7fffu + ((u >> 16) & 1u);
    return (ushort16)(u >> 16);
}

__device__ __forceinline__ uint32 f2bf2pack(float a, float b) {
    return (uint32)f2bf(a) | ((uint32)f2bf(b) << 16);
}

// ---- fused prep: eps, deg histogram, graph starts, z->bf16, zWe1 dot,
// ----             Wt transpose+cast (m=0 c1W1; 1..3 cW0; 4..6 cW1; 7..9 cWe)
__global__ void prep_kernel(const int* __restrict__ pos_batch, const int* __restrict__ batch,
                            const int* __restrict__ dst, const float* __restrict__ z,
                            const float* __restrict__ We1,
                            const float* __restrict__ c1W1, const float* __restrict__ cW0,
                            const float* __restrict__ cW1, const float* __restrict__ cWe,
                            int* __restrict__ eps, int* __restrict__ gs,
                            int* __restrict__ deg, ushort16* __restrict__ zb,
                            float* __restrict__ zWe1, ushort16* __restrict__ Wt) {
    int i = blockIdx.x * blockDim.x + threadIdx.x;
    if (i < cP) {
        int cur = pos_batch[i];
        int prev = (i == 0) ? -1 : pos_batch[i - 1];
        for (int e = prev + 1; e <= cur; ++e) eps[e] = i;
        if (i == cP - 1)
            for (int e = cur + 1; e <= cE; ++e) eps[e] = cP;
    }
    if (i < cE) atomicAdd(&deg[dst[i]], 1);
    if (i < cZV * HID) zb[i] = f2bf(z[i]);
    if (i < cZV) {
        float acc = 0.f;
        #pragma unroll 8
        for (int k = 0; k < HID; ++k) acc += z[i * HID + k] * We1[k];
        zWe1[i] = acc;
    }
    if (i < 10 * HID * HID) {
        int m = i >> 14;            // / (128*128)
        int idx = i & (HID * HID - 1);
        const float* srcp = (m == 0) ? c1W1
                          : (m <= 3) ? (cW0 + (size_t)(m - 1) * HID * HID)
                          : (m <= 6) ? (cW1 + (size_t)(m - 4) * HID * HID)
                                     : (cWe + (size_t)(m - 7) * HID * HID);
        int c = idx >> 7, k = idx & 127;
        Wt[(size_t)m * HID * HID + idx] = f2bf(srcp[(size_t)k * HID + c]);
    }
    if (i <= cG) {
        int lo = 0, hi = cN;
        while (lo < hi) {
            int mid = (lo + hi) >> 1;
            if (batch[mid] < i) lo = mid + 1; else hi = mid;
        }
        gs[i] = lo;
    }
}

// ---- MFMA zWe tables: zWe[l][v][:] = bf16( zb[v][:] @ We[l] ) ----
__global__ __launch_bounds__(256) void zwe_mfma(
    const ushort16* __restrict__ zb,    // [cZV][128] bf16
    const ushort16* __restrict__ WtE,   // [3][128][128] bf16 transposed
    ushort16* __restrict__ zWeb)        // [3][cZV][128] bf16
{
    int l = blockIdx.y;
    const ushort16* Wt = WtE + (size_t)l * HID * HID;
    ushort16* outp = zWeb + (size_t)l * cZV * HID;
    int wv = threadIdx.x >> 6;
    int lane = threadIdx.x & 63;
    int row0 = blockIdx.x * 64 + wv * 16;
    int r = lane & 15;
    int g = lane >> 4;
    int grow = row0 + r;
    bf16x8s zero8 = {0, 0, 0, 0, 0, 0, 0, 0};
    bf16x8s xf[4];
    #pragma unroll
    for (int kk = 0; kk < 4; ++kk)
        xf[kk] = (grow < cZV) ? *(const bf16x8s*)(zb + (size_t)grow * HID + kk * 32 + g * 8)
                              : zero8;
    f32x4 acc[8];
    #pragma unroll
    for (int ct = 0; ct < 8; ++ct) acc[ct] = (f32x4){0.f, 0.f, 0.f, 0.f};
    #pragma unroll
    for (int kk = 0; kk < 4; ++kk) {
        #pragma unroll
        for (int ct = 0; ct < 8; ++ct) {
            bf16x8s wf = *(const bf16x8s*)(Wt + (size_t)(ct * 16 + r) * HID + kk * 32 + g * 8);
            acc[ct] = __builtin_amdgcn_mfma_f32_16x16x32_bf16(wf, xf[kk], acc[ct], 0, 0, 0);
        }
    }
    if (grow < cZV) {
        #pragma unroll
        for (int ct = 0; ct < 8; ++ct) {
            int c0 = ct * 16 + g * 4;
            uint2 pk;
            pk.x = f2bf2pack(acc[ct][0], acc[ct][1]);
            pk.y = f2bf2pack(acc[ct][2], acc[ct][3]);
            *(uint2*)(outp + (size_t)grow * HID + c0) = pk;
        }
    }
}

// ======================= CSR scan chain =======================
__global__ void scan1(const int* __restrict__ deg, int* __restrict__ rowptr,
                      int* __restrict__ bsum) {
    __shared__ int t[512];
    int i = blockIdx.x * 512 + threadIdx.x;
    int v = (i < cN) ? deg[i] : 0;
    t[threadIdx.x] = v;
    __syncthreads();
    for (int off = 1; off < 512; off <<= 1) {
        int add = (threadIdx.x >= off) ? t[threadIdx.x - off] : 0;
        __syncthreads();
        t[threadIdx.x] += add;
        __syncthreads();
    }
    if (i < cN) rowptr[i + 1] = t[threadIdx.x];
    if (threadIdx.x == 511) bsum[blockIdx.x] = t[511];
}

__global__ void scan2(const int* __restrict__ bsum, int* __restrict__ boffs) {
    __shared__ int t[128];
    int i = threadIdx.x;
    int v = (i < NB) ? bsum[i] : 0;
    t[i] = v;
    __syncthreads();
    for (int off = 1; off < 128; off <<= 1) {
        int add = (i >= off) ? t[i - off] : 0;
        __syncthreads();
        t[i] += add;
        __syncthreads();
    }
    if (i < NB) boffs[i] = t[i] - v;   // exclusive prefix
}

__global__ void scan3(int* __restrict__ rowptr, int* __restrict__ cursor,
                      const int* __restrict__ boffs) {
    int i = blockIdx.x * blockDim.x + threadIdx.x;
    if (i == 0) { rowptr[0] = 0; cursor[0] = 0; }
    if (i < cN) {
        int val = rowptr[i + 1] + boffs[i >> 9];
        rowptr[i + 1] = val;
        cursor[i + 1] = val;
    }
}

__global__ void csr_scatter(const int* __restrict__ dst, int* __restrict__ cursor,
                            int* __restrict__ csr_eid) {
    int e = blockIdx.x * blockDim.x + threadIdx.x;
    if (e >= cE) return;
    int p = atomicAdd(&cursor[dst[e]], 1);
    csr_eid[p] = e;
}

// ---- wave-parallel deterministic sort (bitonic over 64 lanes) + erec build ----
// erec[i] = (src, cnt | (pstart<<8), pidx0, bits(penc0))
__device__ __forceinline__ int4 make_erec(int e, const int* __restrict__ src,
                                          const int* __restrict__ eps,
                                          const int* __restrict__ pos_index,
                                          const float* __restrict__ pos_enc) {
    int s = eps[e], t = eps[e + 1];
    int cnt = t - s;
    int4 r;
    r.x = src[e];
    r.y = cnt | (s << 8);
    if (cnt >= 1) { r.z = pos_index[s]; r.w = __float_as_int(pos_enc[s]); }
    else          { r.z = 0;            r.w = 0; }
    return r;
}

__global__ __launch_bounds__(256) void csr_sort_erec_wave(
    const int* __restrict__ rowptr, int* __restrict__ eid,
    const int* __restrict__ src, const int* __restrict__ eps,
    const int* __restrict__ pos_index, const float* __restrict__ pos_enc,
    int4* __restrict__ erec)
{
    int wid = threadIdx.x >> 6;
    int lane = threadIdx.x & 63;
    int n = blockIdx.x * 4 + wid;
    if (n >= cN) return;
    int a = rowptr[n], b = rowptr[n + 1];
    int d = b - a;
    if (d > 64) {
        if (lane == 0) {
            for (int i = a + 1; i < b; ++i) {
                int v = eid[i];
                int j = i - 1;
                while (j >= a && eid[j] > v) { eid[j + 1] = eid[j]; --j; }
                eid[j + 1] = v;
            }
            for (int i = a; i < b; ++i)
                erec[i] = make_erec(eid[i], src, eps, pos_index, pos_enc);
        }
        return;
    }
    int v = (lane < d) ? eid[a + lane] : 0x7fffffff;
    #pragma unroll
    for (int k = 2; k <= 64; k <<= 1) {
        for (int j = k >> 1; j > 0; j >>= 1) {
            int w = __shfl_xor(v, j);
            bool up    = ((lane & k) == 0);
            bool lower = ((lane & j) == 0);
            v = (up == lower) ? min(v, w) : max(v, w);
        }
    }
    if (lane < d)
        erec[a + lane] = make_erec(v, src, eps, pos_index, pos_enc);
}

// ---- per-edge z contribution, 4 channels/lane (half-wave layout) ----
__device__ __forceinline__ float4 zcalc4(int4 r, int l5,
                                         const ushort16* __restrict__ zWe,
                                         const int* __restrict__ pos_index,
                                         const float* __restrict__ pos_enc) {
    float w = __int_as_float(r.w);
    uint2 zu = ((const uint2*)(zWe + (size_t)r.z * HID))[l5];
    float2 za = bf2f2(zu.x), zc = bf2f2(zu.y);
    float4 z;
    z.x = w * za.x; z.y = w * za.y; z.z = w * zc.x; z.w = w * zc.y;
    int cnt = r.y & 255;
    if (cnt >= 2) {
        int s = ((uint32)r.y) >> 8;
        for (int p = s + 1; p < s + cnt; ++p) {
            float wp = pos_enc[p];
            uint2 zp = ((const uint2*)(zWe + (size_t)pos_index[p] * HID))[l5];
            float2 pa = bf2f2(zp.x), pb = bf2f2(zp.y);
            z.x += wp * pa.x; z.y += wp * pa.y; z.z += wp * pb.x; z.w += wp * pb.y;
        }
    }
    return z;
}

__device__ __forceinline__ float zcalc1(int4 r,
                                        const float* __restrict__ zWe1,
                                        const int* __restrict__ pos_index,
                                        const float* __restrict__ pos_enc) {
    float a = __int_as_float(r.w) * zWe1[r.z];
    int cnt = r.y & 255;
    if (cnt >= 2) {
        int s = ((uint32)r.y) >> 8;
        for (int p = s + 1; p < s + cnt; ++p)
            a += pos_enc[p] * zWe1[pos_index[p]];
    }
    return a;
}

// fold one edge (4 channels/lane) into acc
__device__ __forceinline__ void edge_acc(int4 r, uint2 xu, int l5,
                                         const ushort16* __restrict__ zWe,
                                         const int* __restrict__ pos_index,
                                         const float* __restrict__ pos_enc,
                                         float4 b4, float4& acc) {
    float4 z = zcalc4(r, l5, zWe, pos_index, pos_enc);
    float2 xa = bf2f2(xu.x), xc = bf2f2(xu.y);
    acc.x += fmaxf(xa.x + z.x + b4.x, 0.f);
    acc.y += fmaxf(xa.y + z.y + b4.y, 0.f);
    acc.z += fmaxf(xc.x + z.z + b4.z, 0.f);
    acc.w += fmaxf(xc.y + z.w + b4.w, 0.f);
}

// ======================= conv1 (gather, grid-stride, fused node stage A) ============
__global__ __launch_bounds__(256) void conv1_gather(
    const int* __restrict__ rowptr, const int4* __restrict__ erec,
    const int* __restrict__ pos_index, const float* __restrict__ pos_enc,
    const float* __restrict__ zWe1, const float* __restrict__ be1,
    const float* __restrict__ W0, const float* __restrict__ b0,
    ushort16* __restrict__ hb)
{
    int wid = threadIdx.x >> 6;
    int lane = threadIdx.x & 63;
    float be = be1[0];
    float2 w2 = ((const float2*)W0)[lane];
    float2 b2 = ((const float2*)b0)[lane];
    for (int n = blockIdx.x * 4 + wid; n < cN; n += gridDim.x * 4) {
        int e0 = rowptr[n], e1 = rowptr[n + 1];
        float part = 0.f;
        for (int i = e0 + lane; i < e1; i += 64) {
            int4 r = erec[i];
            float a = zcalc1(r, zWe1, pos_index, pos_enc);
            part += fmaxf(1.f + a + be, 0.f);
        }
        #pragma unroll
        for (int off = 32; off > 0; off >>= 1)
            part += __shfl_xor(part, off);
        float h0 = 1.f + part;
        float ox = eluf(h0 * w2.x + b2.x);
        float oy = eluf(h0 * w2.y + b2.y);
        ((uint32*)hb)[(size_t)n * 64 + lane] = f2bf2pack(ox, oy);
    }
}

// ===== convs edge phase: half-wave edge pairing, 8 edges/iter, 4 ch/lane =====
// lanes 0-31 take even-offset edges, 32-63 odd-offset edges of the SAME node;
// cross-half combine via shfl_xor(32). hb[n] = bf16(x[n] + sum relu(...)).
__global__ __launch_bounds__(256) void convs_gather(
    const int* __restrict__ rowptr, const int4* __restrict__ erec,
    const int* __restrict__ pos_index, const float* __restrict__ pos_enc,
    const ushort16* __restrict__ zWe,
    const float* __restrict__ be,
    const float* __restrict__ x,       // fp32 self term
    const ushort16* __restrict__ xb,   // bf16 gather operand
    ushort16* __restrict__ hb)
{
    int wid = threadIdx.x >> 6;
    int lane = threadIdx.x & 63;
    int h  = lane >> 5;       // half id (0: even edges, 1: odd edges)
    int l5 = lane & 31;       // lane within half -> channels 4*l5..4*l5+3
    float4 b4 = ((const float4*)be)[l5];
    for (int n = blockIdx.x * 4 + wid; n < cN; n += gridDim.x * 4) {
        int e0 = rowptr[n], e1 = rowptr[n + 1];
        float4 acc = make_float4(0.f, 0.f, 0.f, 0.f);
        int i = e0;
        // 8 edges/iter: each half takes 4 (unrolled) -> 8 load chains in flight
        for (; i + 8 <= e1; i += 8) {
            int4 r0 = erec[i + h];
            int4 r1 = erec[i + 2 + h];
            int4 r2 = erec[i + 4 + h];
            int4 r3 = erec[i + 6 + h];
            uint2 x0 = ((const uint2*)(xb + (size_t)r0.x * HID))[l5];
            uint2 x1 = ((const uint2*)(xb + (size_t)r1.x * HID))[l5];
            uint2 x2 = ((const uint2*)(xb + (size_t)r2.x * HID))[l5];
            uint2 x3 = ((const uint2*)(xb + (size_t)r3.x * HID))[l5];
            edge_acc(r0, x0, l5, zWe, pos_index, pos_enc, b4, acc);
            edge_acc(r1, x1, l5, zWe, pos_index, pos_enc, b4, acc);
            edge_acc(r2, x2, l5, zWe, pos_index, pos_enc, b4, acc);
            edge_acc(r3, x3, l5, zWe, pos_index, pos_enc, b4, acc);
        }
        // 4 edges: 2 per half
        if (i + 4 <= e1) {
            int4 r0 = erec[i + h];
            int4 r1 = erec[i + 2 + h];
            uint2 x0 = ((const uint2*)(xb + (size_t)r0.x * HID))[l5];
            uint2 x1 = ((const uint2*)(xb + (size_t)r1.x * HID))[l5];
            edge_acc(r0, x0, l5, zWe, pos_index, pos_enc, b4, acc);
            edge_acc(r1, x1, l5, zWe, pos_index, pos_enc, b4, acc);
            i += 4;
        }
        // 2 edges: 1 per half
        if (i + 2 <= e1) {
            int4 r0 = erec[i + h];
            uint2 x0 = ((const uint2*)(xb + (size_t)r0.x * HID))[l5];
            edge_acc(r0, x0, l5, zWe, pos_index, pos_enc, b4, acc);
            i += 2;
        }
        // final odd edge: half A only
        if (i < e1 && h == 0) {
            int4 r0 = erec[i];
            uint2 x0 = ((const uint2*)(xb + (size_t)r0.x * HID))[l5];
            edge_acc(r0, x0, l5, zWe, pos_index, pos_enc, b4, acc);
        }
        // combine halves (partner lane holds same channels)
        acc.x += __shfl_xor(acc.x, 32);
        acc.y += __shfl_xor(acc.y, 32);
        acc.z += __shfl_xor(acc.z, 32);
        acc.w += __shfl_xor(acc.w, 32);
        if (h == 0) {
            float4 xn = ((const float4*)(x + (size_t)n * HID))[l5];
            uint2 pk;
            pk.x = f2bf2pack(xn.x + acc.x, xn.y + acc.y);
            pk.y = f2bf2pack(xn.z + acc.z, xn.w + acc.w);
            ((uint2*)(hb + (size_t)n * HID))[l5] = pk;
        }
    }
}

// ---- swapped-operand MFMA matmul: y = elu(Xb @ W + b) ----
__global__ __launch_bounds__(256) void node_mm_mfma(
    const ushort16* __restrict__ Xb, const ushort16* __restrict__ Wt,
    const float* __restrict__ b,
    float* __restrict__ Y, ushort16* __restrict__ Yb, int M)
{
    int wv = threadIdx.x >> 6;
    int lane = threadIdx.x & 63;
    int row0 = blockIdx.x * 64 + wv * 16;
    int r = lane & 15;
    int g = lane >> 4;
    int grow = row0 + r;
    bf16x8s zero8 = {0, 0, 0, 0, 0, 0, 0, 0};
    bf16x8s xf[4];
    #pragma unroll
    for (int kk = 0; kk < 4; ++kk)
        xf[kk] = (grow < M) ? *(const bf16x8s*)(Xb + (size_t)grow * HID + kk * 32 + g * 8)
                            : zero8;
    f32x4 acc[8];
    #pragma unroll
    for (int ct = 0; ct < 8; ++ct) acc[ct] = (f32x4){0.f, 0.f, 0.f, 0.f};
    #pragma unroll
    for (int kk = 0; kk < 4; ++kk) {
        #pragma unroll
        for (int ct = 0; ct < 8; ++ct) {
            bf16x8s wf = *(const bf16x8s*)(Wt + (size_t)(ct * 16 + r) * HID + kk * 32 + g * 8);
            acc[ct] = __builtin_amdgcn_mfma_f32_16x16x32_bf16(wf, xf[kk], acc[ct], 0, 0, 0);
        }
    }
    if (grow < M) {
        #pragma unroll
        for (int ct = 0; ct < 8; ++ct) {
            int c0 = ct * 16 + g * 4;
            float4 bv = *(const float4*)(b + c0);
            float4 o;
            o.x = eluf(acc[ct][0] + bv.x);
            o.y = eluf(acc[ct][1] + bv.y);
            o.z = eluf(acc[ct][2] + bv.z);
            o.w = eluf(acc[ct][3] + bv.w);
            *(float4*)(Y + (size_t)grow * HID + c0) = o;
            if (Yb) {
                uint2 pk;
                pk.x = f2bf2pack(o.x, o.y);
                pk.y = f2bf2pack(o.z, o.w);
                *(uint2*)(Yb + (size_t)grow * HID + c0) = pk;
            }
        }
    }
}

// ---- fused double MFMA matmul: y = elu(elu(Xb@WA+bA)@WB+bB) ----
__global__ __launch_bounds__(256) void node_mm2_mfma(
    const ushort16* __restrict__ Xb,
    const ushort16* __restrict__ WtA, const float* __restrict__ bA,
    const ushort16* __restrict__ WtB, const float* __restrict__ bB,
    float* __restrict__ Y, ushort16* __restrict__ Yb, int M)
{
    __shared__ float4 TsV[1024];       // 16 KB: 64 rows x 256 B, swizzled
    char* Ts = (char*)TsV;
    int wv = threadIdx.x >> 6;
    int lane = threadIdx.x & 63;
    int row0 = blockIdx.x * 64 + wv * 16;
    int r = lane & 15;
    int g = lane >> 4;
    int grow = row0 + r;
    int rowL = wv * 16 + r;
    bf16x8s zero8 = {0, 0, 0, 0, 0, 0, 0, 0};
    bf16x8s xf[4];
    #pragma unroll
    for (int kk = 0; kk < 4; ++kk)
        xf[kk] = (grow < M) ? *(const bf16x8s*)(Xb + (size_t)grow * HID + kk * 32 + g * 8)
                            : zero8;
    f32x4 acc[8];
    #pragma unroll
    for (int ct = 0; ct < 8; ++ct) acc[ct] = (f32x4){0.f, 0.f, 0.f, 0.f};
    #pragma unroll
    for (int kk = 0; kk < 4; ++kk) {
        #pragma unroll
        for (int ct = 0; ct < 8; ++ct) {
            bf16x8s wf = *(const bf16x8s*)(WtA + (size_t)(ct * 16 + r) * HID + kk * 32 + g * 8);
            acc[ct] = __builtin_amdgcn_mfma_f32_16x16x32_bf16(wf, xf[kk], acc[ct], 0, 0, 0);
        }
    }
    #pragma unroll
    for (int ct = 0; ct < 8; ++ct) {
        int c0 = ct * 16 + g * 4;
        float4 bv = *(const float4*)(bA + c0);
        uint2 pk;
        pk.x = f2bf2pack(eluf(acc[ct][0] + bv.x), eluf(acc[ct][1] + bv.y));
        pk.y = f2bf2pack(eluf(acc[ct][2] + bv.z), eluf(acc[ct][3] + bv.w));
        int boff = (c0 * 2) ^ ((rowL & 7) << 4);
        *(uint2*)(Ts + rowL * 256 + boff) = pk;
    }
    bf16x8s tf[4];
    #pragma unroll
    for (int kk = 0; kk < 4; ++kk) {
        int boff = (kk * 64 + g * 16) ^ ((rowL & 7) << 4);
        tf[kk] = *(const bf16x8s*)(Ts + rowL * 256 + boff);
    }
    #pragma unroll
    for (int ct = 0; ct < 8; ++ct) acc[ct] = (f32x4){0.f, 0.f, 0.f, 0.f};
    #pragma unroll
    for (int kk = 0; kk < 4; ++kk) {
        #pragma unroll
        for (int ct = 0; ct < 8; ++ct) {
            bf16x8s wf = *(const bf16x8s*)(WtB + (size_t)(ct * 16 + r) * HID + kk * 32 + g * 8);
            acc[ct] = __builtin_amdgcn_mfma_f32_16x16x32_bf16(wf, tf[kk], acc[ct], 0, 0, 0);
        }
    }
    if (grow < M) {
        #pragma unroll
        for (int ct = 0; ct < 8; ++ct) {
            int c0 = ct * 16 + g * 4;
            float4 bv = *(const float4*)(bB + c0);
            float4 o;
            o.x = eluf(acc[ct][0] + bv.x);
            o.y = eluf(acc[ct][1] + bv.y);
            o.z = eluf(acc[ct][2] + bv.z);
            o.w = eluf(acc[ct][3] + bv.w);
            *(float4*)(Y + (size_t)grow * HID + c0) = o;
            if (Yb) {
                uint2 pk;
                pk.x = f2bf2pack(o.x, o.y);
                pk.y = f2bf2pack(o.z, o.w);
                *(uint2*)(Yb + (size_t)grow * HID + c0) = pk;
            }
        }
    }
}

// ---- fused pool + head, 512 threads: 4-way node split + k-split matvec ----
__global__ __launch_bounds__(512) void pool_head(
    const float* __restrict__ x, const int* __restrict__ gs,
    const float* __restrict__ W1, const float* __restrict__ b1,
    const float* __restrict__ W2, const float* __restrict__ b2,
    float* __restrict__ out) {
    __shared__ float red[4][HID];
    __shared__ float ps[HID];
    __shared__ float hs[HID];
    int g = blockIdx.x, t = threadIdx.x;
    int part = t >> 7, ch = t & 127;
    int n0 = gs[g], n1 = gs[g + 1];
    float acc = 0.f;
    for (int n = n0 + part; n < n1; n += 4) acc += x[(size_t)n * HID + ch];
    red[part][ch] = acc;
    __syncthreads();
    if (part == 0) ps[ch] = red[0][ch] + red[1][ch] + red[2][ch] + red[3][ch];
    __syncthreads();
    float a = 0.f;
    #pragma unroll 8
    for (int k = part * 32; k < part * 32 + 32; ++k) a += ps[k] * W1[k * HID + ch];
    red[part][ch] = a;
    __syncthreads();
    if (part == 0)
        hs[ch] = eluf(red[0][ch] + red[1][ch] + red[2][ch] + red[3][ch] + b1[ch]);
    __syncthreads();
    if (t < 10) {
        float o = b2[t];
        #pragma unroll 8
        for (int k = 0; k < HID; ++k) o += hs[k] * W2[k * 10 + t];
        out[(size_t)g * 10 + t] = o;
    }
}

extern "C" void kernel_launch(void* const* d_in, const int* in_sizes, int n_in,
                              void* d_out, int out_size, void* d_ws, size_t ws_size,
                              hipStream_t stream) {
    const int*   ei        = (const int*)d_in[0];   // [2][E]
    const int*   batch     = (const int*)d_in[1];   // [N]
    const int*   pos_index = (const int*)d_in[2];   // [P]
    const float* pos_enc   = (const float*)d_in[3]; // [P]
    const int*   pos_batch = (const int*)d_in[4];   // [P]
    const float* z         = (const float*)d_in[5]; // [ZV][H]
    const float* c1W0      = (const float*)d_in[6]; // [1][H]
    const float* c1b0      = (const float*)d_in[7];
    const float* c1W1      = (const float*)d_in[8]; // [H][H]
    const float* c1b1      = (const float*)d_in[9];
    const float* c1We      = (const float*)d_in[10]; // [H][1]
    const float* c1be      = (const float*)d_in[11]; // [1]
    const float* cW0       = (const float*)d_in[12]; // [3][H][H]
    const float* cb0       = (const float*)d_in[13];
    const float* cW1       = (const float*)d_in[14];
    const float* cb1       = (const float*)d_in[15];
    const float* cWe       = (const float*)d_in[16]; // [3][H][H]
    const float* cbe       = (const float*)d_in[17]; // [3][H]
    const float* l1W       = (const float*)d_in[18];
    const float* l1b       = (const float*)d_in[19];
    const float* l2W       = (const float*)d_in[20];
    const float* l2b       = (const float*)d_in[21];
    float* out = (float*)d_out;

    const int* src = ei;
    const int* dst = ei + cE;

    char* ws = (char*)d_ws;
    size_t off = 0;
    auto alloc = [&](size_t bytes) -> void* {
        void* p = ws + off;
        off += (bytes + 511) & ~(size_t)511;
        return p;
    };
    ushort16* zWe3  = (ushort16*)alloc((size_t)3 * cZV * HID * 2);
    float* zWe1     = (float*)alloc((size_t)cZV * 4);
    ushort16* Wt    = (ushort16*)alloc((size_t)10 * HID * HID * 2);
    ushort16* zb    = (ushort16*)alloc((size_t)cZV * HID * 2);
    int*   eps      = (int*)  alloc((size_t)(cE + 1) * 4);
    float* x        = (float*)alloc((size_t)cN * HID * 4);
    ushort16* xbf   = (ushort16*)alloc((size_t)cN * HID * 2);
    ushort16* hbf   = (ushort16*)alloc((size_t)cN * HID * 2);
    int*   deg      = (int*)  alloc((size_t)cN * 4);
    int*   rowptr   = (int*)  alloc((size_t)(cN + 1) * 4);
    int*   cursor   = (int*)  alloc((size_t)(cN + 1) * 4);
    int*   csr_eid  = (int*)  alloc((size_t)cE * 4);
    int4*  erec     = (int4*) alloc((size_t)cE * 16);
    int*   bsum     = (int*)  alloc((size_t)NB * 4);
    int*   boffs    = (int*)  alloc((size_t)NB * 4);
    int*   gs       = (int*)  alloc((size_t)(cG + 1) * 4);

    // prep: eps + deg + gs + z->bf16 + zWe1 + Wt (fused), then zWe tables
    hipMemsetAsync(deg, 0, (size_t)cN * 4, stream);
    prep_kernel<<<(cP + 255) / 256, 256, 0, stream>>>(pos_batch, batch, dst, z, c1We,
                                                      c1W1, cW0, cW1, cWe,
                                                      eps, gs, deg, zb, zWe1, Wt);
    zwe_mfma<<<dim3((cZV + 63) / 64, 3), 256, 0, stream>>>(zb, Wt + (size_t)7 * HID * HID,
                                                           zWe3);

    // CSR build (dst fixed across layers)
    scan1<<<NB, 512, 0, stream>>>(deg, rowptr, bsum);
    scan2<<<1, 128, 0, stream>>>(bsum, boffs);
    scan3<<<(cN + 255) / 256, 256, 0, stream>>>(rowptr, cursor, boffs);
    csr_scatter<<<(cE + 255) / 256, 256, 0, stream>>>(dst, cursor, csr_eid);
    csr_sort_erec_wave<<<(cN + 3) / 4, 256, 0, stream>>>(rowptr, csr_eid, src, eps,
                                                         pos_index, pos_enc, erec);

    // conv1: gather -> hbf, then single MFMA matmul -> x fp32 + xbf
    conv1_gather<<<GATHER_BLOCKS, 256, 0, stream>>>(rowptr, erec, pos_index, pos_enc,
                                                    zWe1, c1be, c1W0, c1b0, hbf);
    node_mm_mfma<<<(cN + 63) / 64, 256, 0, stream>>>(hbf, Wt, c1b1, x, xbf, cN);

    // convs 0..2: gather -> hbf; fused W0+W1 MFMA -> x (+xbf)
    for (int l = 0; l < 3; ++l) {
        convs_gather<<<GATHER_BLOCKS, 256, 0, stream>>>(rowptr, erec, pos_index, pos_enc,
                                                        zWe3 + (size_t)l * cZV * HID,
                                                        cbe + (size_t)l * HID, x, xbf, hbf);
        node_mm2_mfma<<<(cN + 63) / 64, 256, 0, stream>>>(
            hbf,
            Wt + (size_t)(1 + l) * HID * HID, cb0 + (size_t)l * HID,
            Wt + (size_t)(4 + l) * HID * HID, cb1 + (size_t)l * HID,
            x, (l < 2) ? xbf : nullptr, cN);
    }

    // pool + head
    pool_head<<<cG, 512, 0, stream>>>(x, gs, l1W, l1b, l2W, l2b, out);
}